// Round 2
// baseline (230.058 us; speedup 1.0000x reference)
//
#include <hip/hip_runtime.h>
#include <math.h>

#define NPX 4096          // 64*64 low-res pixels per batch
#define H2 128
#define W2 128

// K1: 1x1 conv (256->64), RAW partial sums via atomicAdd (BN+ReLU folded into K2a).
// grid (32 px-chunks, 2 co-halves, 4 ci-quarters), block 256 = 4 waves x 8 co each.
// Thread: 4 consecutive px (float4 x load), 8 co, 64 ci -> 32 atomicAdds.
__global__ __launch_bounds__(256) void k1_conv1x1(
    const float* __restrict__ X, const float* __restrict__ w,
    float* __restrict__ mid)
{
    int lane = threadIdx.x & 63;
    int wg = __builtin_amdgcn_readfirstlane(threadIdx.x >> 6);
    int p4 = blockIdx.x * 256 + lane * 4;      // 0..8191, multiple of 4
    int bb = p4 >> 12;
    int sp = p4 & (NPX - 1);
    int co0 = blockIdx.y * 32 + wg * 8;
    int ci0 = blockIdx.z * 64;

    const float4* xp = (const float4*)X + ((size_t)(bb * 256 + ci0)) * (NPX / 4) + (sp >> 2);
    const float* wp = w + (size_t)co0 * 256 + ci0;

    float acc[8][4];
    #pragma unroll
    for (int j = 0; j < 8; ++j)
        #pragma unroll
        for (int c = 0; c < 4; ++c) acc[j][c] = 0.f;

    #pragma unroll 4
    for (int ci = 0; ci < 64; ++ci) {
        float4 xq = xp[(size_t)ci * (NPX / 4)];
        #pragma unroll
        for (int j = 0; j < 8; ++j) {
            float wv = wp[j * 256 + ci];
            acc[j][0] += xq.x * wv;
            acc[j][1] += xq.y * wv;
            acc[j][2] += xq.z * wv;
            acc[j][3] += xq.w * wv;
        }
    }
    float* op = mid + ((size_t)bb * 64 + co0) * NPX + sp;
    #pragma unroll
    for (int j = 0; j < 8; ++j)
        #pragma unroll
        for (int c = 0; c < 4; ++c)
            atomicAdd(&op[j * NPX + c], acc[j][c]);
}

// K2a: 3x3 conv (64->100) with BN+ReLU applied to `mid` during LDS staging.
// grid (25 co-quads, 8 tiles(4 spatial x 2 batch), 2 ci-halves), block 256.
// Tile 32x32 px; thread = 2x2 px block x 4 co -> acc[4px][4co] = 16 VGPRs.
// Weights staged once in LDS (4co x 32ci x 9 packed as [ci][k][co4] for b128
// broadcast reads); mid halo staged per 8-ci chunk.
__global__ __launch_bounds__(256) void k2a_conv3x3(
    const float* __restrict__ mid, const float* __restrict__ ew,
    const float* __restrict__ g, const float* __restrict__ bt,
    const float* __restrict__ m, const float* __restrict__ var,
    float* __restrict__ enc)
{
    __shared__ float wlds[32 * 9 * 4];     // [ci][k][j]  4.6 KB
    __shared__ float mt[8 * 34 * 35];      // [ci][r][c] pitch 35, 38 KB

    int tid = threadIdx.x;
    int cq = blockIdx.x;                   // 0..24 -> co = 4*cq + j
    int t = blockIdx.y;
    int bb = t >> 2;
    int tile = t & 3;
    int ty0 = (tile >> 1) * 32, tx0 = (tile & 1) * 32;
    int cib = blockIdx.z * 32;

    // stage weights once
    for (int idx = tid; idx < 1152; idx += 256) {
        int j = idx & 3;
        int k = (idx >> 2) % 9;
        int ci = idx / 36;
        wlds[idx] = ew[((size_t)(4 * cq + j) * 64 + cib + ci) * 9 + k];
    }

    float acc[4][4];                       // [s][j]
    #pragma unroll
    for (int s = 0; s < 4; ++s)
        #pragma unroll
        for (int j = 0; j < 4; ++j) acc[s][j] = 0.f;

    int qy = tid >> 4, qx = tid & 15;

    for (int cc = 0; cc < 4; ++cc) {
        __syncthreads();
        // stage 8 ci x 34x34 halo with BN+ReLU folded in
        for (int idx = tid; idx < 9248; idx += 256) {
            int ci = idx / 1156;
            int rem = idx - ci * 1156;
            int r = rem / 34, c = rem - r * 34;
            int gci = cib + cc * 8 + ci;
            int gy = ty0 + r - 1, gx = tx0 + c - 1;
            float v = 0.f;
            if ((unsigned)gy < 64u && (unsigned)gx < 64u) {
                float inv = g[gci] * rsqrtf(var[gci] + 1e-5f);
                float b2 = bt[gci] - m[gci] * inv;
                v = fmaxf(mid[((size_t)bb * 64 + gci) * NPX + gy * 64 + gx] * inv + b2, 0.f);
            }
            mt[ci * 1190 + r * 35 + c] = v;
        }
        __syncthreads();

        #pragma unroll 2
        for (int ci = 0; ci < 8; ++ci) {
            float p[4][4];
            #pragma unroll
            for (int r = 0; r < 4; ++r)
                #pragma unroll
                for (int c = 0; c < 4; ++c)
                    p[r][c] = mt[ci * 1190 + (2 * qy + r) * 35 + (2 * qx + c)];
            const float4* wq = (const float4*)&wlds[(cc * 8 + ci) * 36];
            #pragma unroll
            for (int k = 0; k < 9; ++k) {
                float4 w4 = wq[k];
                int dy = k / 3, dx = k % 3;
                float p00 = p[dy][dx],     p01 = p[dy][dx + 1];
                float p10 = p[dy + 1][dx], p11 = p[dy + 1][dx + 1];
                acc[0][0] += p00 * w4.x; acc[0][1] += p00 * w4.y; acc[0][2] += p00 * w4.z; acc[0][3] += p00 * w4.w;
                acc[1][0] += p01 * w4.x; acc[1][1] += p01 * w4.y; acc[1][2] += p01 * w4.z; acc[1][3] += p01 * w4.w;
                acc[2][0] += p10 * w4.x; acc[2][1] += p10 * w4.y; acc[2][2] += p10 * w4.z; acc[2][3] += p10 * w4.w;
                acc[3][0] += p11 * w4.x; acc[3][1] += p11 * w4.y; acc[3][2] += p11 * w4.z; acc[3][3] += p11 * w4.w;
            }
        }
    }

    int oy = ty0 + 2 * qy, ox = tx0 + 2 * qx;
    #pragma unroll
    for (int s = 0; s < 4; ++s) {
        int yy = oy + (s >> 1), xx = ox + (s & 1);
        #pragma unroll
        for (int j = 0; j < 4; ++j)
            atomicAdd(&enc[((size_t)bb * 100 + 4 * cq + j) * NPX + yy * 64 + xx], acc[s][j]);
    }
}

// K2b: BN + clamp + pow + softmax over 25 taps.
// Output layout wn[b][s*25+k][px] so stores (here) and loads (K3) are coalesced.
__global__ __launch_bounds__(256) void k2b_softmax(
    const float* __restrict__ enc,
    const float* __restrict__ g, const float* __restrict__ bt,
    const float* __restrict__ m, const float* __restrict__ var,
    const float* __restrict__ power_p,
    float* __restrict__ wn)
{
    int tid = threadIdx.x;
    int s = tid >> 6;
    int p = blockIdx.x * 64 + (tid & 63);
    int bb = p >> 12, sp = p & (NPX - 1);
    float pw = fmaxf(power_p[0], 1e-5f);
    float tv[25];
    float mx = -1e30f;
    #pragma unroll
    for (int k = 0; k < 25; ++k) {
        int co = 4 * k + s;
        float inv = g[co] * rsqrtf(var[co] + 1e-5f);
        float e = enc[((size_t)bb * 100 + co) * NPX + sp] * inv + (bt[co] - m[co] * inv);
        e = fmaxf(e, 1e-5f);
        float x = exp2f(pw * log2f(e));
        tv[k] = x;
        mx = fmaxf(mx, x);
    }
    float sum = 0.f;
    #pragma unroll
    for (int k = 0; k < 25; ++k) {
        float e = expf(tv[k] - mx);
        tv[k] = e;
        sum += e;
    }
    float r = 1.0f / sum;
    #pragma unroll
    for (int k = 0; k < 25; ++k)
        wn[((size_t)bb * 100 + s * 25 + k) * NPX + sp] = tv[k] * r;
}

// K3: reassembly. grid (32 spatial, 16 ch-chunks), block 256 = 16x16 low-res px.
// wv[100] loaded coalesced from wn[b][j][px]; X halo tile in LDS per 16-ch chunk.
__global__ __launch_bounds__(256, 2) void k3_carafe(
    const float* __restrict__ X, const float* __restrict__ wn,
    float* __restrict__ out)
{
    __shared__ float xt[16 * 400];   // 16 ch x 20x20 halo tile, 25.6 KB
    int tid = threadIdx.x;
    int bx = blockIdx.x;
    int bb = bx >> 4;
    int t = bx & 15;
    int ty0 = (t >> 2) * 16, tx0 = (t & 3) * 16;
    int c0 = blockIdx.y * 16;
    for (int idx = tid; idx < 6400; idx += 256) {
        int ch = idx / 400;
        int rem = idx - ch * 400;
        int r = rem / 20, cc = rem - r * 20;
        int gy = ty0 + r - 2, gx = tx0 + cc - 2;
        float val = 0.f;
        if ((unsigned)gy < 64u && (unsigned)gx < 64u)
            val = X[((size_t)bb * 256 + c0 + ch) * NPX + gy * 64 + gx];
        xt[idx] = val;
    }
    int ylq = tid >> 4, xlq = tid & 15;
    int yl = ty0 + ylq, xl = tx0 + xlq;
    int px = yl * 64 + xl;
    float wv[100];
    #pragma unroll
    for (int j = 0; j < 100; ++j)
        wv[j] = wn[((size_t)bb * 100 + j) * NPX + px];
    __syncthreads();
    for (int ch = 0; ch < 16; ++ch) {
        float x[25];
        #pragma unroll
        for (int ki = 0; ki < 5; ++ki)
            #pragma unroll
            for (int kj = 0; kj < 5; ++kj)
                x[ki * 5 + kj] = xt[ch * 400 + (ylq + ki) * 20 + (xlq + kj)];
        float a0 = 0.f, a1 = 0.f, a2 = 0.f, a3 = 0.f;
        #pragma unroll
        for (int k = 0; k < 25; ++k) {
            a0 += wv[k]      * x[k];
            a1 += wv[25 + k] * x[k];
            a2 += wv[50 + k] * x[k];
            a3 += wv[75 + k] * x[k];
        }
        float* ob = out + ((size_t)(bb * 256 + c0 + ch) * H2 + 2 * yl) * W2 + 2 * xl;
        *(float2*)ob        = make_float2(a0, a1);
        *(float2*)(ob + W2) = make_float2(a2, a3);
    }
}

extern "C" void kernel_launch(void* const* d_in, const int* in_sizes, int n_in,
                              void* d_out, int out_size, void* d_ws, size_t ws_size,
                              hipStream_t stream)
{
    const float* X  = (const float*)d_in[0];
    const float* cw = (const float*)d_in[1];
    const float* cg = (const float*)d_in[2];
    const float* cb = (const float*)d_in[3];
    const float* cm = (const float*)d_in[4];
    const float* cv = (const float*)d_in[5];
    const float* ew = (const float*)d_in[6];
    const float* eg = (const float*)d_in[7];
    const float* eb = (const float*)d_in[8];
    const float* em = (const float*)d_in[9];
    const float* ev = (const float*)d_in[10];
    const float* pp = (const float*)d_in[11];
    float* out = (float*)d_out;

    float* ws  = (float*)d_ws;
    float* mid = ws;                        // 2*64*4096   = 524288 floats (raw conv sums)
    float* enc = ws + 524288;               // 2*100*4096  = 819200 floats (raw conv sums)
    float* wn  = ws + 524288 + 819200;      // 2*100*4096  = 819200 floats

    // zero mid + enc (both accumulated via atomics)
    hipMemsetAsync(ws, 0, (524288 + 819200) * sizeof(float), stream);
    k1_conv1x1<<<dim3(32, 2, 4), 256, 0, stream>>>(X, cw, mid);
    k2a_conv3x3<<<dim3(25, 8, 2), 256, 0, stream>>>(mid, ew, cg, cb, cm, cv, enc);
    k2b_softmax<<<dim3(128), 256, 0, stream>>>(enc, eg, eb, em, ev, pp, wn);
    k3_carafe<<<dim3(32, 16), 256, 0, stream>>>(X, wn, out);
}

// Round 3
// 191.394 us; speedup vs baseline: 1.2020x; 1.2020x over previous
//
#include <hip/hip_runtime.h>
#include <math.h>

#define NPX 4096          // 64*64 low-res pixels per batch
#define H2 128
#define W2 128

// K1: 1x1 conv (256->64) + BN + ReLU fused. No atomics.
// grid (64 px-chunks of 128, 8 co-octets), block 256 = 2 wave-pairs:
// waves 0-1 = ci 0..127, waves 2-3 = ci 128..255; LDS reduce, BN, store.
__global__ __launch_bounds__(256) void k1_conv1x1(
    const float* __restrict__ X, const float* __restrict__ w,
    const float* __restrict__ g, const float* __restrict__ bt,
    const float* __restrict__ m, const float* __restrict__ var,
    float* __restrict__ mid)
{
    __shared__ float wl[256 * 8];   // [ci][j]  8 KB
    __shared__ float red[8 * 128];  // [j][pxl] 4 KB

    int tid = threadIdx.x;
    int cih = tid >> 7;             // 0/1, wave-pair uniform
    int pxl = tid & 127;
    int p = blockIdx.x * 128 + pxl;
    int bb = p >> 12, sp = p & (NPX - 1);
    int co0 = blockIdx.y * 8;
    int ci0 = cih * 128;

    for (int idx = tid; idx < 2048; idx += 256) {
        int j = idx & 7, ci = idx >> 3;
        wl[idx] = w[(size_t)(co0 + j) * 256 + ci];
    }
    __syncthreads();

    float acc[8];
    #pragma unroll
    for (int j = 0; j < 8; ++j) acc[j] = 0.f;

    const float* xp = X + ((size_t)bb * 256 + ci0) * NPX + sp;
    #pragma unroll 8
    for (int ci = 0; ci < 128; ++ci) {
        float x = xp[(size_t)ci * NPX];
        const float4* wq = (const float4*)&wl[(ci0 + ci) * 8];
        float4 w0 = wq[0], w1 = wq[1];
        acc[0] += x * w0.x; acc[1] += x * w0.y; acc[2] += x * w0.z; acc[3] += x * w0.w;
        acc[4] += x * w1.x; acc[5] += x * w1.y; acc[6] += x * w1.z; acc[7] += x * w1.w;
    }

    if (cih == 1) {
        #pragma unroll
        for (int j = 0; j < 8; ++j) red[j * 128 + pxl] = acc[j];
    }
    __syncthreads();
    if (cih == 0) {
        #pragma unroll
        for (int j = 0; j < 8; ++j) {
            int co = co0 + j;
            float a = acc[j] + red[j * 128 + pxl];
            float inv = g[co] * rsqrtf(var[co] + 1e-5f);
            a = fmaxf(a * inv + (bt[co] - m[co] * inv), 0.f);
            mid[((size_t)bb * 64 + co) * NPX + sp] = a;
        }
    }
}

// K2a: 3x3 conv (64->100) on pre-activated mid. No atomics (full 64-ci in block).
// grid (25 co-quads, 16 tiles x 2 batch) = 800 blocks, block 256 = 16x16 px.
// Thread: 1 px, 4 co. Weights in LDS [ci][k][j4] read as uniform float4
// broadcasts; mid halo (18x18, pitch 19) staged per 16-ci chunk.
__global__ __launch_bounds__(256) void k2a_conv3x3(
    const float* __restrict__ mid, const float* __restrict__ ew,
    float* __restrict__ enc)
{
    __shared__ float wl[64 * 9 * 4];     // 9.2 KB
    __shared__ float mt[16 * 18 * 19];   // 21.9 KB, pitch 19

    int tid = threadIdx.x;
    int cq = blockIdx.x;                 // co = 4*cq + j
    int t = blockIdx.y;
    int bb = t >> 4;
    int tile = t & 15;
    int ty0 = (tile >> 2) * 16, tx0 = (tile & 3) * 16;
    int qy = tid >> 4, qx = tid & 15;

    for (int idx = tid; idx < 2304; idx += 256) {
        int j = idx & 3;
        int kk = (idx >> 2) % 9;
        int ci = idx / 36;
        wl[idx] = ew[((size_t)(4 * cq + j) * 64 + ci) * 9 + kk];
    }

    float acc[4];
    #pragma unroll
    for (int j = 0; j < 4; ++j) acc[j] = 0.f;

    for (int cc = 0; cc < 4; ++cc) {
        __syncthreads();
        for (int idx = tid; idx < 5184; idx += 256) {   // 16 ci x 18x18
            int ci = idx / 324;
            int rem = idx - ci * 324;
            int r = rem / 18, c = rem - r * 18;
            int gy = ty0 + r - 1, gx = tx0 + c - 1;
            float v = 0.f;
            if ((unsigned)gy < 64u && (unsigned)gx < 64u)
                v = mid[((size_t)bb * 64 + cc * 16 + ci) * NPX + gy * 64 + gx];
            mt[ci * 342 + r * 19 + c] = v;
        }
        __syncthreads();

        #pragma unroll 2
        for (int ci = 0; ci < 16; ++ci) {
            int base = ci * 342 + qy * 19 + qx;
            float nb[9];
            #pragma unroll
            for (int dy = 0; dy < 3; ++dy) {
                nb[dy * 3 + 0] = mt[base + dy * 19 + 0];
                nb[dy * 3 + 1] = mt[base + dy * 19 + 1];
                nb[dy * 3 + 2] = mt[base + dy * 19 + 2];
            }
            const float4* wq = (const float4*)&wl[(cc * 16 + ci) * 36];
            #pragma unroll
            for (int k = 0; k < 9; ++k) {
                float4 w4 = wq[k];
                acc[0] += nb[k] * w4.x;
                acc[1] += nb[k] * w4.y;
                acc[2] += nb[k] * w4.z;
                acc[3] += nb[k] * w4.w;
            }
        }
    }

    int sp = (ty0 + qy) * 64 + tx0 + qx;
    #pragma unroll
    for (int j = 0; j < 4; ++j)
        enc[((size_t)bb * 100 + 4 * cq + j) * NPX + sp] = acc[j];
}

// K2b: BN + clamp + pow + softmax over 25 taps. wn layout [b][s*25+k][px].
// grid 512, block 64: block = (px-chunk of 64, subpos s).
__global__ __launch_bounds__(64) void k2b_softmax(
    const float* __restrict__ enc,
    const float* __restrict__ g, const float* __restrict__ bt,
    const float* __restrict__ m, const float* __restrict__ var,
    const float* __restrict__ power_p,
    float* __restrict__ wn)
{
    int s = blockIdx.x & 3;
    int p = (blockIdx.x >> 2) * 64 + threadIdx.x;
    int bb = p >> 12, sp = p & (NPX - 1);
    float pw = fmaxf(power_p[0], 1e-5f);
    float tv[25];
    float mx = -1e30f;
    #pragma unroll
    for (int k = 0; k < 25; ++k) {
        int co = 4 * k + s;
        float inv = g[co] * rsqrtf(var[co] + 1e-5f);
        float e = enc[((size_t)bb * 100 + co) * NPX + sp] * inv + (bt[co] - m[co] * inv);
        e = fmaxf(e, 1e-5f);
        float x = exp2f(pw * log2f(e));
        tv[k] = x;
        mx = fmaxf(mx, x);
    }
    float sum = 0.f;
    #pragma unroll
    for (int k = 0; k < 25; ++k) {
        float e = expf(tv[k] - mx);
        tv[k] = e;
        sum += e;
    }
    float r = 1.0f / sum;
    #pragma unroll
    for (int k = 0; k < 25; ++k)
        wn[((size_t)bb * 100 + s * 25 + k) * NPX + sp] = tv[k] * r;
}

// K3: reassembly. grid (32 spatial, 16 ch-chunks), block 256 = 16x16 low-res px.
__global__ __launch_bounds__(256, 2) void k3_carafe(
    const float* __restrict__ X, const float* __restrict__ wn,
    float* __restrict__ out)
{
    __shared__ float xt[16 * 400];   // 16 ch x 20x20 halo tile, 25.6 KB
    int tid = threadIdx.x;
    int bx = blockIdx.x;
    int bb = bx >> 4;
    int t = bx & 15;
    int ty0 = (t >> 2) * 16, tx0 = (t & 3) * 16;
    int c0 = blockIdx.y * 16;
    for (int idx = tid; idx < 6400; idx += 256) {
        int ch = idx / 400;
        int rem = idx - ch * 400;
        int r = rem / 20, cc = rem - r * 20;
        int gy = ty0 + r - 2, gx = tx0 + cc - 2;
        float val = 0.f;
        if ((unsigned)gy < 64u && (unsigned)gx < 64u)
            val = X[((size_t)bb * 256 + c0 + ch) * NPX + gy * 64 + gx];
        xt[idx] = val;
    }
    int ylq = tid >> 4, xlq = tid & 15;
    int yl = ty0 + ylq, xl = tx0 + xlq;
    int px = yl * 64 + xl;
    float wv[100];
    #pragma unroll
    for (int j = 0; j < 100; ++j)
        wv[j] = wn[((size_t)bb * 100 + j) * NPX + px];
    __syncthreads();
    for (int ch = 0; ch < 16; ++ch) {
        float x[25];
        #pragma unroll
        for (int ki = 0; ki < 5; ++ki)
            #pragma unroll
            for (int kj = 0; kj < 5; ++kj)
                x[ki * 5 + kj] = xt[ch * 400 + (ylq + ki) * 20 + (xlq + kj)];
        float a0 = 0.f, a1 = 0.f, a2 = 0.f, a3 = 0.f;
        #pragma unroll
        for (int k = 0; k < 25; ++k) {
            a0 += wv[k]      * x[k];
            a1 += wv[25 + k] * x[k];
            a2 += wv[50 + k] * x[k];
            a3 += wv[75 + k] * x[k];
        }
        float* ob = out + ((size_t)(bb * 256 + c0 + ch) * H2 + 2 * yl) * W2 + 2 * xl;
        *(float2*)ob        = make_float2(a0, a1);
        *(float2*)(ob + W2) = make_float2(a2, a3);
    }
}

extern "C" void kernel_launch(void* const* d_in, const int* in_sizes, int n_in,
                              void* d_out, int out_size, void* d_ws, size_t ws_size,
                              hipStream_t stream)
{
    const float* X  = (const float*)d_in[0];
    const float* cw = (const float*)d_in[1];
    const float* cg = (const float*)d_in[2];
    const float* cb = (const float*)d_in[3];
    const float* cm = (const float*)d_in[4];
    const float* cv = (const float*)d_in[5];
    const float* ew = (const float*)d_in[6];
    const float* eg = (const float*)d_in[7];
    const float* eb = (const float*)d_in[8];
    const float* em = (const float*)d_in[9];
    const float* ev = (const float*)d_in[10];
    const float* pp = (const float*)d_in[11];
    float* out = (float*)d_out;

    float* ws  = (float*)d_ws;
    float* mid = ws;                        // 2*64*4096   floats (BN+ReLU applied)
    float* enc = ws + 524288;               // 2*100*4096  floats (raw conv sums)
    float* wn  = ws + 524288 + 819200;      // 2*100*4096  floats

    k1_conv1x1<<<dim3(64, 8), 256, 0, stream>>>(X, cw, cg, cb, cm, cv, mid);
    k2a_conv3x3<<<dim3(25, 32), 256, 0, stream>>>(mid, ew, enc);
    k2b_softmax<<<dim3(512), 64, 0, stream>>>(enc, eg, eb, em, ev, pp, wn);
    k3_carafe<<<dim3(32, 16), 256, 0, stream>>>(X, wn, out);
}